// Round 16
// baseline (691.000 us; speedup 1.0000x reference)
//
#include <hip/hip_runtime.h>
#include <hip/hip_bf16.h>
#include <hip/hip_fp16.h>
#include <math.h>

// Shapes: x [128,20000,1] f32; rows/cols [640000] i32; vals [640000] f32
// W_gc [20,10]; b_gc [10]; W_fc [200000,10]; b_fc [10]; out [128,10] f32.
//
// fp16 Chebyshev planes (X16 [g][n][k][64]) + fp32 2-slot carry (C32).
// BCG=64 -> one edge-gather = one full 128B line (minimal line traffic).
// R16: proj_fc reads W_gc/b_gc/W_fc through wave-uniform (scalar) loads --
// no LDS staging, freeing the LDS/vector pipes (R14 showed it LDS-issue-bound).

#define NF 10
#define KCHEB 20
#define BCG 64                        // batch elems per chunk
#define COFF16 (KCHEB * BCG)          // 1280 fp16 elems per node in X16

typedef unsigned int u32;

// ---------------- CSR build ----------------

__global__ void init_kernel(int* counts, float* h_part, int N, int H) {
    int i = blockIdx.x * blockDim.x + threadIdx.x;
    if (i < N) counts[i] = 0;
    if (i < H) h_part[i] = 0.f;
}

__global__ void hist_kernel(const int* __restrict__ rows, int* __restrict__ counts, int E) {
    int e = blockIdx.x * blockDim.x + threadIdx.x;
    if (e < E) atomicAdd(&counts[rows[e]], 1);
}

#define SCAN_THREADS 1024
__global__ void scan_kernel(const int* __restrict__ counts, int* __restrict__ row_start,
                            int* __restrict__ cursor, int N) {
    __shared__ int sh[SCAN_THREADS];
    int t = threadIdx.x;
    int CH = (N + SCAN_THREADS - 1) / SCAN_THREADS;
    int base = t * CH;
    int sum = 0;
    for (int i = 0; i < CH; ++i) {
        int idx = base + i;
        sum += (idx < N) ? counts[idx] : 0;
    }
    sh[t] = sum;
    __syncthreads();
    for (int off = 1; off < SCAN_THREADS; off <<= 1) {
        int v = (t >= off) ? sh[t - off] : 0;
        __syncthreads();
        sh[t] += v;
        __syncthreads();
    }
    int run = (t == 0) ? 0 : sh[t - 1];
    for (int i = 0; i < CH; ++i) {
        int idx = base + i;
        if (idx < N) {
            int v = counts[idx];
            row_start[idx] = run;
            cursor[idx] = run;
            run += v;
        }
    }
    if (t == SCAN_THREADS - 1) row_start[N] = run;
}

// csr[p] = (col*COFF16 [element offset of node's X16 row], bits(val))
__global__ void scatter_kernel(const int* __restrict__ rows, const int* __restrict__ cols,
                               const float* __restrict__ vals, int* __restrict__ cursor,
                               int2* __restrict__ csr, int E) {
    int e = blockIdx.x * blockDim.x + threadIdx.x;
    if (e >= E) return;
    int p = atomicAdd(&cursor[rows[e]], 1);
    csr[p] = make_int2(cols[e] * COFF16, __float_as_int(vals[e]));
}

// ---------------- T0 fill (tiled transpose; fp16 plane 0 + fp32 carry 0) ----

__global__ void transpose_kernel(const float* __restrict__ x, __half* __restrict__ X16,
                                 float* __restrict__ C32, int N, int ntiles, int b0s) {
    __shared__ float tile[BCG][65];
    int tid = threadIdx.x;
    int g = blockIdx.x / ntiles;
    int ti = blockIdx.x - g * ntiles;
    int n0 = ti * 64;
#pragma unroll
    for (int p = 0; p < 16; ++p) {
        int idx = p * 256 + tid;
        int row = idx >> 6;        // batch offset 0..63
        int col = idx & 63;        // node offset 0..63
        if (n0 + col < N)
            tile[row][col] = x[(size_t)(b0s + g * BCG + row) * N + n0 + col];
    }
    __syncthreads();
#pragma unroll
    for (int p = 0; p < 16; ++p) {
        int idx = p * 256 + tid;
        int nloc = idx >> 6;       // node offset 0..63
        int bb = idx & 63;         // batch offset 0..63
        int n = n0 + nloc;
        if (n < N) {
            float v = tile[bb][nloc];
            X16[(size_t)(g * N + n) * COFF16 + bb] = __float2half_rn(v);   // plane k=0
            C32[((size_t)(g * 2 + 0) * N + n) * BCG + bb] = v;             // carry slot 0
        }
    }
}

// ---------------- SpMM step ----------------
// Block = 256 thr = 32 rows x 8 bq lanes; each lane gathers 8 fp16 (16B), so a
// row's 8 lanes consume exactly one 128B line per edge.
// Carry math fp32 via C32 rotating slots; outputs: C32[k&1] + X16 plane k.

__global__ __launch_bounds__(256)
void spmm_kernel(__half* __restrict__ X16, float* __restrict__ C32,
                 const int* __restrict__ row_start, const int2* __restrict__ csr,
                 int N, int xpcShift, int subsPerChunk,
                 int kIn, int kOut, float alpha, float beta) {
    int xcd = blockIdx.x & 7;
    int chunk = xcd >> xpcShift;
    int xpcMask = (1 << xpcShift) - 1;
    int sub = (blockIdx.x >> 3) * (1 << xpcShift) + (xcd & xpcMask);
    if (sub >= subsPerChunk) return;
    int tid = threadIdx.x;
    int ln = tid >> 3;             // row 0..31
    int bq = tid & 7;              // 8 lanes x 8 fp16 = 64 batch
    int n = sub * 32 + ln;
    if (n >= N) return;
    int s = row_start[n];
    int e = row_start[n + 1];

    const __half* gin = X16 + (size_t)chunk * N * COFF16;
    int koff = kIn * BCG + bq * 8; // gather element offset within node row
    int bo = bq * 8;
    float acc[8];
#pragma unroll
    for (int q = 0; q < 8; ++q) acc[q] = 0.f;

    int i = s;
    for (; i + 4 <= e; i += 4) {
        int2 p0 = csr[i], p1 = csr[i + 1], p2 = csr[i + 2], p3 = csr[i + 3];
        uint4 u0 = *(const uint4*)(gin + p0.x + koff);
        uint4 u1 = *(const uint4*)(gin + p1.x + koff);
        uint4 u2 = *(const uint4*)(gin + p2.x + koff);
        uint4 u3 = *(const uint4*)(gin + p3.x + koff);
        float v0 = __int_as_float(p0.y), v1 = __int_as_float(p1.y);
        float v2 = __int_as_float(p2.y), v3 = __int_as_float(p3.y);
        {
            float2 f0 = __half22float2(*(__half2*)&u0.x), f1 = __half22float2(*(__half2*)&u0.y);
            float2 f2 = __half22float2(*(__half2*)&u0.z), f3 = __half22float2(*(__half2*)&u0.w);
            acc[0] += v0 * f0.x; acc[1] += v0 * f0.y; acc[2] += v0 * f1.x; acc[3] += v0 * f1.y;
            acc[4] += v0 * f2.x; acc[5] += v0 * f2.y; acc[6] += v0 * f3.x; acc[7] += v0 * f3.y;
        }
        {
            float2 f0 = __half22float2(*(__half2*)&u1.x), f1 = __half22float2(*(__half2*)&u1.y);
            float2 f2 = __half22float2(*(__half2*)&u1.z), f3 = __half22float2(*(__half2*)&u1.w);
            acc[0] += v1 * f0.x; acc[1] += v1 * f0.y; acc[2] += v1 * f1.x; acc[3] += v1 * f1.y;
            acc[4] += v1 * f2.x; acc[5] += v1 * f2.y; acc[6] += v1 * f3.x; acc[7] += v1 * f3.y;
        }
        {
            float2 f0 = __half22float2(*(__half2*)&u2.x), f1 = __half22float2(*(__half2*)&u2.y);
            float2 f2 = __half22float2(*(__half2*)&u2.z), f3 = __half22float2(*(__half2*)&u2.w);
            acc[0] += v2 * f0.x; acc[1] += v2 * f0.y; acc[2] += v2 * f1.x; acc[3] += v2 * f1.y;
            acc[4] += v2 * f2.x; acc[5] += v2 * f2.y; acc[6] += v2 * f3.x; acc[7] += v2 * f3.y;
        }
        {
            float2 f0 = __half22float2(*(__half2*)&u3.x), f1 = __half22float2(*(__half2*)&u3.y);
            float2 f2 = __half22float2(*(__half2*)&u3.z), f3 = __half22float2(*(__half2*)&u3.w);
            acc[0] += v3 * f0.x; acc[1] += v3 * f0.y; acc[2] += v3 * f1.x; acc[3] += v3 * f1.y;
            acc[4] += v3 * f2.x; acc[5] += v3 * f2.y; acc[6] += v3 * f3.x; acc[7] += v3 * f3.y;
        }
    }
    for (; i < e; ++i) {
        int2 p0 = csr[i];
        uint4 u0 = *(const uint4*)(gin + p0.x + koff);
        float v0 = __int_as_float(p0.y);
        float2 f0 = __half22float2(*(__half2*)&u0.x), f1 = __half22float2(*(__half2*)&u0.y);
        float2 f2 = __half22float2(*(__half2*)&u0.z), f3 = __half22float2(*(__half2*)&u0.w);
        acc[0] += v0 * f0.x; acc[1] += v0 * f0.y; acc[2] += v0 * f1.x; acc[3] += v0 * f1.y;
        acc[4] += v0 * f2.x; acc[5] += v0 * f2.y; acc[6] += v0 * f3.x; acc[7] += v0 * f3.y;
    }

    // carry slot: (k-2)&1 == k&1, so read T_{k-2} and write T_k at the SAME
    // address (thread-private location -> safe).
    float* cslot = C32 + ((size_t)(chunk * 2 + (kOut & 1)) * N + n) * BCG + bo;
    float o[8];
#pragma unroll
    for (int q = 0; q < 8; ++q) o[q] = alpha * acc[q];
    if (beta != 0.f) {
        const float4 pv0 = *(const float4*)(cslot);
        const float4 pv1 = *(const float4*)(cslot + 4);
        o[0] += beta * pv0.x; o[1] += beta * pv0.y; o[2] += beta * pv0.z; o[3] += beta * pv0.w;
        o[4] += beta * pv1.x; o[5] += beta * pv1.y; o[6] += beta * pv1.z; o[7] += beta * pv1.w;
    }
    *(float4*)(cslot)     = make_float4(o[0], o[1], o[2], o[3]);
    *(float4*)(cslot + 4) = make_float4(o[4], o[5], o[6], o[7]);
    __half* o16 = X16 + (size_t)(chunk * N + n) * COFF16 + kOut * BCG + bo;
    uint4 h4;
    __half2 h01 = __floats2half2_rn(o[0], o[1]);
    __half2 h23 = __floats2half2_rn(o[2], o[3]);
    __half2 h45 = __floats2half2_rn(o[4], o[5]);
    __half2 h67 = __floats2half2_rn(o[6], o[7]);
    h4.x = *(u32*)&h01; h4.y = *(u32*)&h23; h4.z = *(u32*)&h45; h4.w = *(u32*)&h67;
    *(uint4*)o16 = h4;
}

// ---------------- Fused projection + FC partial ----------------
// Block = 256 thr = 4 node-slots (one wave each) x 64 bb. The node index is
// wave-uniform (readfirstlane-forced), so ALL weight reads (W_gc, b_gc, W_fc
// row) are scalar loads through the constant cache -- zero LDS in the inner
// loop, vector pipe does only X16 loads + fma.

__global__ __launch_bounds__(256, 4)
void proj_fc_kernel(const __half* __restrict__ X16,
                    const float* __restrict__ W_gc,
                    const float* __restrict__ b_gc,
                    const float* __restrict__ W_fc,
                    float* __restrict__ h_part,
                    int N, int b0s, int G) {
    __shared__ float sRed[BCG * 11];          // stride 11: conflict-free atomics
    int tid = threadIdx.x;
    for (int i = tid; i < BCG * 11; i += 256) sRed[i] = 0.f;
    __syncthreads();

    int g = blockIdx.x % G;
    int bidx = blockIdx.x / G;
    int nblk = gridDim.x / G;

    int bb = tid & (BCG - 1);
    int ln = __builtin_amdgcn_readfirstlane(tid >> 6);   // wave-uniform slot 0..3

    float h_loc[NF];
#pragma unroll
    for (int f = 0; f < NF; ++f) h_loc[f] = 0.f;

    const __half* chunkBase = X16 + (size_t)g * N * COFF16;
    int ngroups = (N + 3) / 4;
    for (int grp = bidx; grp < ngroups; grp += nblk) {
        int n = grp * 4 + ln;                 // wave-uniform
        if (n >= N) continue;                 // wave-uniform branch
        float xt[KCHEB];
        const __half* xp = chunkBase + (size_t)n * COFF16 + bb;
#pragma unroll
        for (int k = 0; k < KCHEB; ++k) xt[k] = __half2float(xp[k * BCG]);
        const float* wrow = W_fc + (size_t)n * (NF * NF);   // wave-uniform addr
#pragma unroll
        for (int j = 0; j < NF; ++j) {
            float gc = b_gc[j];               // scalar load
#pragma unroll
            for (int k = 0; k < KCHEB; ++k) gc += xt[k] * W_gc[k * NF + j]; // s_load
            gc = fmaxf(gc, 0.f);
#pragma unroll
            for (int f = 0; f < NF; ++f) h_loc[f] += gc * wrow[j * NF + f]; // s_load
        }
    }
#pragma unroll
    for (int f = 0; f < NF; ++f) atomicAdd(&sRed[bb * 11 + f], h_loc[f]);
    __syncthreads();
    for (int i = tid; i < BCG * NF; i += 256) {
        int rb = i / NF;
        int rf = i - rb * NF;
        atomicAdd(&h_part[(size_t)(b0s + g * BCG + rb) * NF + rf], sRed[rb * 11 + rf]);
    }
}

// ---------------- Bias + ReLU + softmax ----------------

__global__ void softmax_kernel(const float* __restrict__ h_part, const float* __restrict__ b_fc,
                               float* __restrict__ out, int B) {
    int b = blockIdx.x * blockDim.x + threadIdx.x;
    if (b >= B) return;
    float v[NF];
    float m = -1e30f;
#pragma unroll
    for (int f = 0; f < NF; ++f) {
        float t = fmaxf(h_part[b * NF + f] + b_fc[f], 0.f);
        v[f] = t;
        m = fmaxf(m, t);
    }
    float s = 0.f;
#pragma unroll
    for (int f = 0; f < NF; ++f) { v[f] = expf(v[f] - m); s += v[f]; }
    float inv = 1.f / s;
#pragma unroll
    for (int f = 0; f < NF; ++f) out[b * NF + f] = v[f] * inv;
}

// ---------------- launch ----------------

extern "C" void kernel_launch(void* const* d_in, const int* in_sizes, int n_in,
                              void* d_out, int out_size, void* d_ws, size_t ws_size,
                              hipStream_t stream) {
    const float* x    = (const float*)d_in[0];
    const int*   rows = (const int*)d_in[1];
    const int*   cols = (const int*)d_in[2];
    const float* vals = (const float*)d_in[3];
    const float* W_gc = (const float*)d_in[4];
    const float* b_gc = (const float*)d_in[5];
    const float* W_fc = (const float*)d_in[6];
    const float* b_fc = (const float*)d_in[7];
    float* out = (float*)d_out;

    const int E = in_sizes[1];
    const int N = in_sizes[6] / (NF * NF);
    const int B = in_sizes[0] / N;

    // ---- workspace carve ----
    char* p = (char*)d_ws;
    int* counts    = (int*)p;   p += sizeof(int) * (size_t)N;
    int* row_start = (int*)p;   p += sizeof(int) * (size_t)(N + 1);
    int* cursor    = (int*)p;   p += sizeof(int) * (size_t)N;
    p = (char*)(((size_t)p + 15) & ~(size_t)15);
    int2* csr      = (int2*)p;  p += sizeof(int2) * (size_t)E;
    float* h_part  = (float*)p; p += sizeof(float) * (size_t)B * NF;
    size_t fixed = (size_t)(p - (char*)d_ws);
    fixed = (fixed + 255) & ~(size_t)255;

    // G chunks of BCG=64 resident (G in {2,1}); B=128 -> G=2, single pass
    size_t perChunk16 = (size_t)N * COFF16 * sizeof(__half);     // 51.2 MB
    size_t perCarry   = (size_t)2 * N * BCG * sizeof(float);     // 10.24 MB
    int G = (B >= 2 * BCG) ? 2 : 1;
    while (G > 1 && fixed + (size_t)G * (perChunk16 + perCarry) > ws_size) G >>= 1;
    __half* X16 = (__half*)((char*)d_ws + fixed);
    size_t x16b = ((size_t)G * perChunk16 + 255) & ~(size_t)255;
    float* C32 = (float*)((char*)d_ws + fixed + x16b);
    int xpcShift = (G == 2) ? 2 : 3;
    int BT = G * BCG;
    int nsc = B / BT;

    // ---- CSR build ----
    {
        int H = B * NF;
        int cov = (N > H) ? N : H;
        init_kernel<<<(cov + 255) / 256, 256, 0, stream>>>(counts, h_part, N, H);
        hist_kernel<<<(E + 255) / 256, 256, 0, stream>>>(rows, counts, E);
        scan_kernel<<<1, SCAN_THREADS, 0, stream>>>(counts, row_start, cursor, N);
        scatter_kernel<<<(E + 255) / 256, 256, 0, stream>>>(rows, cols, vals, cursor, csr, E);
    }

    int ntiles = (N + 63) / 64;
    int subsPerChunk = (N + 31) / 32;
    int xpc = 1 << xpcShift;
    int gridSpmm = 8 * ((subsPerChunk + xpc - 1) / xpc);

    for (int c = 0; c < nsc; ++c) {
        int b0s = c * BT;
        transpose_kernel<<<G * ntiles, 256, 0, stream>>>(x, X16, C32, N, ntiles, b0s);
        for (int k = 1; k < KCHEB; ++k) {
            float alpha = (k == 1) ? 1.f : 2.f;
            float beta  = (k == 1) ? 0.f : -1.f;
            spmm_kernel<<<gridSpmm, 256, 0, stream>>>(
                X16, C32, row_start, csr, N, xpcShift, subsPerChunk,
                k - 1, k, alpha, beta);
        }
        proj_fc_kernel<<<512 * G, 256, 0, stream>>>(X16, W_gc, b_gc, W_fc, h_part, N, b0s, G);
    }

    softmax_kernel<<<1, 128, 0, stream>>>(h_part, b_fc, out, B);
}

// Round 17
// 594.891 us; speedup vs baseline: 1.1616x; 1.1616x over previous
//
#include <hip/hip_runtime.h>
#include <hip/hip_bf16.h>
#include <hip/hip_fp16.h>
#include <math.h>

// Shapes: x [128,20000,1] f32; rows/cols [640000] i32; vals [640000] f32
// W_gc [20,10]; b_gc [10]; W_fc [200000,10]; b_fc [10]; out [128,10] f32.
//
// Best-known configuration (R14, 597us):
//  - fp16 Chebyshev planes X16 [g][n][k][64]; fp32 2-slot rotating carry C32.
//  - BCG=64 -> one edge-gather = 64 x 2B = one full 128B cache line (minimum
//    possible line traffic: 2E lines/step). spmm ~25us/step = cross-XCD L3
//    line-service floor (survived MLP/nt/tile-sweep attacks unchanged).
//  - proj_fc: LDS-staged weights ([j][k] W_gc^T for b128 reads; W_fc rows
//    padded [slot][j][12]); sRed stride 11. LDS-issue-bound at ~61us.

#define NF 10
#define KCHEB 20
#define BCG 64                        // batch elems per chunk
#define COFF16 (KCHEB * BCG)          // 1280 fp16 elems per node in X16

typedef unsigned int u32;

// ---------------- CSR build ----------------

__global__ void init_kernel(int* counts, float* h_part, int N, int H) {
    int i = blockIdx.x * blockDim.x + threadIdx.x;
    if (i < N) counts[i] = 0;
    if (i < H) h_part[i] = 0.f;
}

__global__ void hist_kernel(const int* __restrict__ rows, int* __restrict__ counts, int E) {
    int e = blockIdx.x * blockDim.x + threadIdx.x;
    if (e < E) atomicAdd(&counts[rows[e]], 1);
}

#define SCAN_THREADS 1024
__global__ void scan_kernel(const int* __restrict__ counts, int* __restrict__ row_start,
                            int* __restrict__ cursor, int N) {
    __shared__ int sh[SCAN_THREADS];
    int t = threadIdx.x;
    int CH = (N + SCAN_THREADS - 1) / SCAN_THREADS;
    int base = t * CH;
    int sum = 0;
    for (int i = 0; i < CH; ++i) {
        int idx = base + i;
        sum += (idx < N) ? counts[idx] : 0;
    }
    sh[t] = sum;
    __syncthreads();
    for (int off = 1; off < SCAN_THREADS; off <<= 1) {
        int v = (t >= off) ? sh[t - off] : 0;
        __syncthreads();
        sh[t] += v;
        __syncthreads();
    }
    int run = (t == 0) ? 0 : sh[t - 1];
    for (int i = 0; i < CH; ++i) {
        int idx = base + i;
        if (idx < N) {
            int v = counts[idx];
            row_start[idx] = run;
            cursor[idx] = run;
            run += v;
        }
    }
    if (t == SCAN_THREADS - 1) row_start[N] = run;
}

// csr[p] = (col*COFF16 [element offset of node's X16 row], bits(val))
__global__ void scatter_kernel(const int* __restrict__ rows, const int* __restrict__ cols,
                               const float* __restrict__ vals, int* __restrict__ cursor,
                               int2* __restrict__ csr, int E) {
    int e = blockIdx.x * blockDim.x + threadIdx.x;
    if (e >= E) return;
    int p = atomicAdd(&cursor[rows[e]], 1);
    csr[p] = make_int2(cols[e] * COFF16, __float_as_int(vals[e]));
}

// ---------------- T0 fill (tiled transpose; fp16 plane 0 + fp32 carry 0) ----

__global__ void transpose_kernel(const float* __restrict__ x, __half* __restrict__ X16,
                                 float* __restrict__ C32, int N, int ntiles, int b0s) {
    __shared__ float tile[BCG][65];
    int tid = threadIdx.x;
    int g = blockIdx.x / ntiles;
    int ti = blockIdx.x - g * ntiles;
    int n0 = ti * 64;
#pragma unroll
    for (int p = 0; p < 16; ++p) {
        int idx = p * 256 + tid;
        int row = idx >> 6;        // batch offset 0..63
        int col = idx & 63;        // node offset 0..63
        if (n0 + col < N)
            tile[row][col] = x[(size_t)(b0s + g * BCG + row) * N + n0 + col];
    }
    __syncthreads();
#pragma unroll
    for (int p = 0; p < 16; ++p) {
        int idx = p * 256 + tid;
        int nloc = idx >> 6;       // node offset 0..63
        int bb = idx & 63;         // batch offset 0..63
        int n = n0 + nloc;
        if (n < N) {
            float v = tile[bb][nloc];
            X16[(size_t)(g * N + n) * COFF16 + bb] = __float2half_rn(v);   // plane k=0
            C32[((size_t)(g * 2 + 0) * N + n) * BCG + bb] = v;             // carry slot 0
        }
    }
}

// ---------------- SpMM step ----------------
// Block = 256 thr = 32 rows x 8 bq lanes; each lane gathers 8 fp16 (16B), so a
// row's 8 lanes consume exactly one 128B line per edge.
// Carry math fp32 via C32 rotating slots; outputs: C32[k&1] + X16 plane k.

__global__ __launch_bounds__(256)
void spmm_kernel(__half* __restrict__ X16, float* __restrict__ C32,
                 const int* __restrict__ row_start, const int2* __restrict__ csr,
                 int N, int xpcShift, int subsPerChunk,
                 int kIn, int kOut, float alpha, float beta) {
    int xcd = blockIdx.x & 7;
    int chunk = xcd >> xpcShift;
    int xpcMask = (1 << xpcShift) - 1;
    int sub = (blockIdx.x >> 3) * (1 << xpcShift) + (xcd & xpcMask);
    if (sub >= subsPerChunk) return;
    int tid = threadIdx.x;
    int ln = tid >> 3;             // row 0..31
    int bq = tid & 7;              // 8 lanes x 8 fp16 = 64 batch
    int n = sub * 32 + ln;
    if (n >= N) return;
    int s = row_start[n];
    int e = row_start[n + 1];

    const __half* gin = X16 + (size_t)chunk * N * COFF16;
    int koff = kIn * BCG + bq * 8; // gather element offset within node row
    int bo = bq * 8;
    float acc[8];
#pragma unroll
    for (int q = 0; q < 8; ++q) acc[q] = 0.f;

    int i = s;
    for (; i + 4 <= e; i += 4) {
        int2 p0 = csr[i], p1 = csr[i + 1], p2 = csr[i + 2], p3 = csr[i + 3];
        uint4 u0 = *(const uint4*)(gin + p0.x + koff);
        uint4 u1 = *(const uint4*)(gin + p1.x + koff);
        uint4 u2 = *(const uint4*)(gin + p2.x + koff);
        uint4 u3 = *(const uint4*)(gin + p3.x + koff);
        float v0 = __int_as_float(p0.y), v1 = __int_as_float(p1.y);
        float v2 = __int_as_float(p2.y), v3 = __int_as_float(p3.y);
        {
            float2 f0 = __half22float2(*(__half2*)&u0.x), f1 = __half22float2(*(__half2*)&u0.y);
            float2 f2 = __half22float2(*(__half2*)&u0.z), f3 = __half22float2(*(__half2*)&u0.w);
            acc[0] += v0 * f0.x; acc[1] += v0 * f0.y; acc[2] += v0 * f1.x; acc[3] += v0 * f1.y;
            acc[4] += v0 * f2.x; acc[5] += v0 * f2.y; acc[6] += v0 * f3.x; acc[7] += v0 * f3.y;
        }
        {
            float2 f0 = __half22float2(*(__half2*)&u1.x), f1 = __half22float2(*(__half2*)&u1.y);
            float2 f2 = __half22float2(*(__half2*)&u1.z), f3 = __half22float2(*(__half2*)&u1.w);
            acc[0] += v1 * f0.x; acc[1] += v1 * f0.y; acc[2] += v1 * f1.x; acc[3] += v1 * f1.y;
            acc[4] += v1 * f2.x; acc[5] += v1 * f2.y; acc[6] += v1 * f3.x; acc[7] += v1 * f3.y;
        }
        {
            float2 f0 = __half22float2(*(__half2*)&u2.x), f1 = __half22float2(*(__half2*)&u2.y);
            float2 f2 = __half22float2(*(__half2*)&u2.z), f3 = __half22float2(*(__half2*)&u2.w);
            acc[0] += v2 * f0.x; acc[1] += v2 * f0.y; acc[2] += v2 * f1.x; acc[3] += v2 * f1.y;
            acc[4] += v2 * f2.x; acc[5] += v2 * f2.y; acc[6] += v2 * f3.x; acc[7] += v2 * f3.y;
        }
        {
            float2 f0 = __half22float2(*(__half2*)&u3.x), f1 = __half22float2(*(__half2*)&u3.y);
            float2 f2 = __half22float2(*(__half2*)&u3.z), f3 = __half22float2(*(__half2*)&u3.w);
            acc[0] += v3 * f0.x; acc[1] += v3 * f0.y; acc[2] += v3 * f1.x; acc[3] += v3 * f1.y;
            acc[4] += v3 * f2.x; acc[5] += v3 * f2.y; acc[6] += v3 * f3.x; acc[7] += v3 * f3.y;
        }
    }
    for (; i < e; ++i) {
        int2 p0 = csr[i];
        uint4 u0 = *(const uint4*)(gin + p0.x + koff);
        float v0 = __int_as_float(p0.y);
        float2 f0 = __half22float2(*(__half2*)&u0.x), f1 = __half22float2(*(__half2*)&u0.y);
        float2 f2 = __half22float2(*(__half2*)&u0.z), f3 = __half22float2(*(__half2*)&u0.w);
        acc[0] += v0 * f0.x; acc[1] += v0 * f0.y; acc[2] += v0 * f1.x; acc[3] += v0 * f1.y;
        acc[4] += v0 * f2.x; acc[5] += v0 * f2.y; acc[6] += v0 * f3.x; acc[7] += v0 * f3.y;
    }

    // carry slot: (k-2)&1 == k&1, so read T_{k-2} and write T_k at the SAME
    // address (thread-private location -> safe).
    float* cslot = C32 + ((size_t)(chunk * 2 + (kOut & 1)) * N + n) * BCG + bo;
    float o[8];
#pragma unroll
    for (int q = 0; q < 8; ++q) o[q] = alpha * acc[q];
    if (beta != 0.f) {
        const float4 pv0 = *(const float4*)(cslot);
        const float4 pv1 = *(const float4*)(cslot + 4);
        o[0] += beta * pv0.x; o[1] += beta * pv0.y; o[2] += beta * pv0.z; o[3] += beta * pv0.w;
        o[4] += beta * pv1.x; o[5] += beta * pv1.y; o[6] += beta * pv1.z; o[7] += beta * pv1.w;
    }
    *(float4*)(cslot)     = make_float4(o[0], o[1], o[2], o[3]);
    *(float4*)(cslot + 4) = make_float4(o[4], o[5], o[6], o[7]);
    __half* o16 = X16 + (size_t)(chunk * N + n) * COFF16 + kOut * BCG + bo;
    uint4 h4;
    __half2 h01 = __floats2half2_rn(o[0], o[1]);
    __half2 h23 = __floats2half2_rn(o[2], o[3]);
    __half2 h45 = __floats2half2_rn(o[4], o[5]);
    __half2 h67 = __floats2half2_rn(o[6], o[7]);
    h4.x = *(u32*)&h01; h4.y = *(u32*)&h23; h4.z = *(u32*)&h45; h4.w = *(u32*)&h67;
    *(uint4*)o16 = h4;
}

// ---------------- Fused projection + FC partial ----------------
// Block = 256 thr = 4 node-slots x 64 bb. Reads fp16 planes (halved traffic).
// W_gc transposed [j][k] (b128 LDS reads), W_fc staged padded [slot][j][12],
// sRed stride 11 (gcd(11,32)=1, no bank conflicts).

__global__ __launch_bounds__(256, 4)
void proj_fc_kernel(const __half* __restrict__ X16,
                    const float* __restrict__ W_gc,
                    const float* __restrict__ b_gc,
                    const float* __restrict__ W_fc,
                    float* __restrict__ h_part,
                    int N, int b0s, int G) {
    __shared__ float sWgT[NF * KCHEB];       // [j][k]
    __shared__ float sbg[NF];
    __shared__ float sRed[BCG * 11];
    __shared__ float sWf[4 * NF * 12];       // [slot][j][12]
    int tid = threadIdx.x;
    if (tid < KCHEB * NF) sWgT[(tid % NF) * KCHEB + tid / NF] = W_gc[tid];
    if (tid < NF) sbg[tid] = b_gc[tid];
    for (int i = tid; i < BCG * 11; i += 256) sRed[i] = 0.f;
    __syncthreads();

    int g = blockIdx.x % G;
    int bidx = blockIdx.x / G;
    int nblk = gridDim.x / G;

    int bb = tid & (BCG - 1);
    int ln = tid >> 6;                        // node slot 0..3

    float h_loc[NF];
#pragma unroll
    for (int f = 0; f < NF; ++f) h_loc[f] = 0.f;

    const __half* chunkBase = X16 + (size_t)g * N * COFF16;
    int ngroups = (N + 3) / 4;
    for (int grp = bidx; grp < ngroups; grp += nblk) {
        int n0 = grp * 4;
        int lim = (N - n0 < 4 ? N - n0 : 4) * (NF * NF);
        int o = tid * 4;
        if (o < lim) {
            float4 w = *(const float4*)(W_fc + (size_t)n0 * (NF * NF) + o);
            int slot = o / 100;
            int rem = o - slot * 100;
            int j = rem / 10;
            int f = rem - j * 10;
            float wv[4] = { w.x, w.y, w.z, w.w };
#pragma unroll
            for (int q = 0; q < 4; ++q) {
                sWf[slot * 120 + j * 12 + f] = wv[q];
                if (++f == 10) { f = 0; if (++j == 10) { j = 0; ++slot; } }
            }
        }
        __syncthreads();

        int n = n0 + ln;
        if (n < N) {
            float xt[KCHEB];
            const __half* xp = chunkBase + (size_t)n * COFF16 + bb;
#pragma unroll
            for (int k = 0; k < KCHEB; ++k) xt[k] = __half2float(xp[k * BCG]);
            const float* wrow = sWf + ln * 120;
#pragma unroll
            for (int j = 0; j < NF; ++j) {
                const float4 g0 = *(const float4*)(sWgT + j * KCHEB + 0);
                const float4 g1 = *(const float4*)(sWgT + j * KCHEB + 4);
                const float4 g2 = *(const float4*)(sWgT + j * KCHEB + 8);
                const float4 g3 = *(const float4*)(sWgT + j * KCHEB + 12);
                const float4 g4 = *(const float4*)(sWgT + j * KCHEB + 16);
                float gc = sbg[j]
                    + g0.x * xt[0]  + g0.y * xt[1]  + g0.z * xt[2]  + g0.w * xt[3]
                    + g1.x * xt[4]  + g1.y * xt[5]  + g1.z * xt[6]  + g1.w * xt[7]
                    + g2.x * xt[8]  + g2.y * xt[9]  + g2.z * xt[10] + g2.w * xt[11]
                    + g3.x * xt[12] + g3.y * xt[13] + g3.z * xt[14] + g3.w * xt[15]
                    + g4.x * xt[16] + g4.y * xt[17] + g4.z * xt[18] + g4.w * xt[19];
                gc = fmaxf(gc, 0.f);
                const float4 w0 = *(const float4*)(wrow + j * 12 + 0);
                const float4 w1 = *(const float4*)(wrow + j * 12 + 4);
                const float2 w2 = *(const float2*)(wrow + j * 12 + 8);
                h_loc[0] += gc * w0.x; h_loc[1] += gc * w0.y;
                h_loc[2] += gc * w0.z; h_loc[3] += gc * w0.w;
                h_loc[4] += gc * w1.x; h_loc[5] += gc * w1.y;
                h_loc[6] += gc * w1.z; h_loc[7] += gc * w1.w;
                h_loc[8] += gc * w2.x; h_loc[9] += gc * w2.y;
            }
        }
        __syncthreads();
    }
#pragma unroll
    for (int f = 0; f < NF; ++f) atomicAdd(&sRed[bb * 11 + f], h_loc[f]);
    __syncthreads();
    for (int i = tid; i < BCG * NF; i += 256) {
        int rb = i / NF;
        int rf = i - rb * NF;
        atomicAdd(&h_part[(size_t)(b0s + g * BCG + rb) * NF + rf], sRed[rb * 11 + rf]);
    }
}

// ---------------- Bias + ReLU + softmax ----------------

__global__ void softmax_kernel(const float* __restrict__ h_part, const float* __restrict__ b_fc,
                               float* __restrict__ out, int B) {
    int b = blockIdx.x * blockDim.x + threadIdx.x;
    if (b >= B) return;
    float v[NF];
    float m = -1e30f;
#pragma unroll
    for (int f = 0; f < NF; ++f) {
        float t = fmaxf(h_part[b * NF + f] + b_fc[f], 0.f);
        v[f] = t;
        m = fmaxf(m, t);
    }
    float s = 0.f;
#pragma unroll
    for (int f = 0; f < NF; ++f) { v[f] = expf(v[f] - m); s += v[f]; }
    float inv = 1.f / s;
#pragma unroll
    for (int f = 0; f < NF; ++f) out[b * NF + f] = v[f] * inv;
}

// ---------------- launch ----------------

extern "C" void kernel_launch(void* const* d_in, const int* in_sizes, int n_in,
                              void* d_out, int out_size, void* d_ws, size_t ws_size,
                              hipStream_t stream) {
    const float* x    = (const float*)d_in[0];
    const int*   rows = (const int*)d_in[1];
    const int*   cols = (const int*)d_in[2];
    const float* vals = (const float*)d_in[3];
    const float* W_gc = (const float*)d_in[4];
    const float* b_gc = (const float*)d_in[5];
    const float* W_fc = (const float*)d_in[6];
    const float* b_fc = (const float*)d_in[7];
    float* out = (float*)d_out;

    const int E = in_sizes[1];
    const int N = in_sizes[6] / (NF * NF);
    const int B = in_sizes[0] / N;

    // ---- workspace carve ----
    char* p = (char*)d_ws;
    int* counts    = (int*)p;   p += sizeof(int) * (size_t)N;
    int* row_start = (int*)p;   p += sizeof(int) * (size_t)(N + 1);
    int* cursor    = (int*)p;   p += sizeof(int) * (size_t)N;
    p = (char*)(((size_t)p + 15) & ~(size_t)15);
    int2* csr      = (int2*)p;  p += sizeof(int2) * (size_t)E;
    float* h_part  = (float*)p; p += sizeof(float) * (size_t)B * NF;
    size_t fixed = (size_t)(p - (char*)d_ws);
    fixed = (fixed + 255) & ~(size_t)255;

    // G chunks of BCG=64 resident (G in {2,1}); B=128 -> G=2, single pass
    size_t perChunk16 = (size_t)N * COFF16 * sizeof(__half);     // 51.2 MB
    size_t perCarry   = (size_t)2 * N * BCG * sizeof(float);     // 10.24 MB
    int G = (B >= 2 * BCG) ? 2 : 1;
    while (G > 1 && fixed + (size_t)G * (perChunk16 + perCarry) > ws_size) G >>= 1;
    __half* X16 = (__half*)((char*)d_ws + fixed);
    size_t x16b = ((size_t)G * perChunk16 + 255) & ~(size_t)255;
    float* C32 = (float*)((char*)d_ws + fixed + x16b);
    int xpcShift = (G == 2) ? 2 : 3;
    int BT = G * BCG;
    int nsc = B / BT;

    // ---- CSR build ----
    {
        int H = B * NF;
        int cov = (N > H) ? N : H;
        init_kernel<<<(cov + 255) / 256, 256, 0, stream>>>(counts, h_part, N, H);
        hist_kernel<<<(E + 255) / 256, 256, 0, stream>>>(rows, counts, E);
        scan_kernel<<<1, SCAN_THREADS, 0, stream>>>(counts, row_start, cursor, N);
        scatter_kernel<<<(E + 255) / 256, 256, 0, stream>>>(rows, cols, vals, cursor, csr, E);
    }

    int ntiles = (N + 63) / 64;
    int subsPerChunk = (N + 31) / 32;
    int xpc = 1 << xpcShift;
    int gridSpmm = 8 * ((subsPerChunk + xpc - 1) / xpc);

    for (int c = 0; c < nsc; ++c) {
        int b0s = c * BT;
        transpose_kernel<<<G * ntiles, 256, 0, stream>>>(x, X16, C32, N, ntiles, b0s);
        for (int k = 1; k < KCHEB; ++k) {
            float alpha = (k == 1) ? 1.f : 2.f;
            float beta  = (k == 1) ? 0.f : -1.f;
            spmm_kernel<<<gridSpmm, 256, 0, stream>>>(
                X16, C32, row_start, csr, N, xpcShift, subsPerChunk,
                k - 1, k, alpha, beta);
        }
        proj_fc_kernel<<<512 * G, 256, 0, stream>>>(X16, W_gc, b_gc, W_fc, h_part, N, b0s, G);
    }

    softmax_kernel<<<1, 128, 0, stream>>>(h_part, b_fc, out, B);
}